// Round 1
// baseline (21121.654 us; speedup 1.0000x reference)
//
#include <hip/hip_runtime.h>
#include <hip/hip_bf16.h>
#include <math.h>

// ---------------------------------------------------------------------------
// NewLLMFlexible: embed->LN -> 2x[concat(x,ctx)->Lin+ReLU->Lin+ReLU->gates->ctxLN]
//                 -> logits GEMM (H=4096 -> V=32000)
// Round 0 baseline: fp32 vector-ALU GEMM (128x128 tile, 8x8 microtile).
// NOTE: block-1 gates/ctx are dead code w.r.t. logits -> skipped.
// ---------------------------------------------------------------------------

#define T_TOK 4096   // B*S
#define E_DIM 1024
#define C_DIM 1024
#define H_DIM 4096
#define V_DIM 32000
#define LN_EPS 1e-5f

// ---------------- block-wide mean/var (256 threads = 4 waves) ----------------
__device__ __forceinline__ void block_meanvar(float s, float s2, float n,
                                              float& mean, float& var) {
  __shared__ float red[16];
#pragma unroll
  for (int o = 32; o > 0; o >>= 1) {
    s  += __shfl_down(s, o, 64);
    s2 += __shfl_down(s2, o, 64);
  }
  const int lane = threadIdx.x & 63;
  const int w    = threadIdx.x >> 6;
  if (lane == 0) { red[w] = s; red[8 + w] = s2; }
  __syncthreads();
  s  = red[0] + red[1] + red[2] + red[3];
  s2 = red[8] + red[9] + red[10] + red[11];
  mean = s / n;
  var  = s2 / n - mean * mean;
}

// ---------------- embed gather + LN -> hcat[:, 0:E]; zero hcat[:, E:] --------
__global__ __launch_bounds__(256) void embed_ln_kernel(
    const int* __restrict__ ids, const float* __restrict__ table,
    const float* __restrict__ g, const float* __restrict__ b,
    float* __restrict__ hcat) {
  const int t   = blockIdx.x;
  const int tid = threadIdx.x;
  const float4 v = ((const float4*)(table + (long)ids[t] * E_DIM))[tid];
  float s  = v.x + v.y + v.z + v.w;
  float s2 = v.x * v.x + v.y * v.y + v.z * v.z + v.w * v.w;
  float mean, var;
  block_meanvar(s, s2, (float)E_DIM, mean, var);
  const float inv = 1.0f / sqrtf(var + LN_EPS);
  const float4 gv = ((const float4*)g)[tid];
  const float4 bv = ((const float4*)b)[tid];
  float4 o;
  o.x = (v.x - mean) * inv * gv.x + bv.x;
  o.y = (v.y - mean) * inv * gv.y + bv.y;
  o.z = (v.z - mean) * inv * gv.z + bv.z;
  o.w = (v.w - mean) * inv * gv.w + bv.w;
  float* out = hcat + (long)t * (E_DIM + C_DIM);
  ((float4*)out)[tid] = o;
  ((float4*)(out + E_DIM))[tid] = make_float4(0.f, 0.f, 0.f, 0.f);  // ctx0 = 0
}

// ---------------- ctx = LN(f*ctx + i*delta) * cg + cb, in-place in hcat ------
__global__ __launch_bounds__(256) void ctx_ln_kernel(
    const float* __restrict__ fbuf, const float* __restrict__ ibuf,
    const float* __restrict__ dbuf,
    const float* __restrict__ cg, const float* __restrict__ cb,
    float* __restrict__ hcat) {
  const int t   = blockIdx.x;
  const int tid = threadIdx.x;
  const long o1 = (long)t * C_DIM;
  const float4 fv = ((const float4*)(fbuf + o1))[tid];
  const float4 iv = ((const float4*)(ibuf + o1))[tid];
  const float4 dv = ((const float4*)(dbuf + o1))[tid];
  float* ctx = hcat + (long)t * (E_DIM + C_DIM) + E_DIM;
  const float4 cv = ((const float4*)ctx)[tid];
  float4 u;
  u.x = fv.x * cv.x + iv.x * dv.x;
  u.y = fv.y * cv.y + iv.y * dv.y;
  u.z = fv.z * cv.z + iv.z * dv.z;
  u.w = fv.w * cv.w + iv.w * dv.w;
  float s  = u.x + u.y + u.z + u.w;
  float s2 = u.x * u.x + u.y * u.y + u.z * u.z + u.w * u.w;
  float mean, var;
  block_meanvar(s, s2, (float)C_DIM, mean, var);
  const float inv = 1.0f / sqrtf(var + LN_EPS);
  const float4 gv = ((const float4*)cg)[tid];
  const float4 bv = ((const float4*)cb)[tid];
  float4 o;
  o.x = (u.x - mean) * inv * gv.x + bv.x;
  o.y = (u.y - mean) * inv * gv.y + bv.y;
  o.z = (u.z - mean) * inv * gv.z + bv.z;
  o.w = (u.w - mean) * inv * gv.w + bv.w;
  ((float4*)ctx)[tid] = o;
}

// ---------------- fp32 GEMM: C = act(A[MxK] @ B[KxN] + bias) -----------------
// 128x128 tile, BK=8, 256 threads, 8x8 microtile/thread.
// ACT: 0=none 1=relu 2=tanh 3=sigmoid
template <int ACT>
__global__ __launch_bounds__(256) void gemm_bias_act(
    const float* __restrict__ A, const float* __restrict__ B,
    const float* __restrict__ bias, float* __restrict__ C,
    int M, int N, int K) {
  __shared__ float As[8][132];  // [k][m], +4 pad: transposed-store conflicts <=2-way
  __shared__ float Bs[8][128];  // [k][n]
  const int tid = threadIdx.x;
  const int tx  = tid & 15;   // n micro-block
  const int ty  = tid >> 4;   // m micro-block
  const int bn0 = blockIdx.x * 128;
  const int bm0 = blockIdx.y * 128;

  const int arow = tid >> 1;          // 0..127
  const int acol = (tid & 1) << 2;    // 0 or 4
  const int brow = tid >> 5;          // 0..7
  const int bcol = (tid & 31) << 2;   // 0..124

  const float* Ap = A + (long)(bm0 + arow) * K + acol;
  const float* Bp = B + (long)brow * N + bn0 + bcol;

  float acc[8][8];
#pragma unroll
  for (int i = 0; i < 8; ++i)
#pragma unroll
    for (int j = 0; j < 8; ++j) acc[i][j] = 0.f;

  for (int k0 = 0; k0 < K; k0 += 8) {
    const float4 av = *(const float4*)Ap;  Ap += 8;
    const float4 bv = *(const float4*)Bp;  Bp += (long)8 * N;
    As[acol + 0][arow] = av.x;
    As[acol + 1][arow] = av.y;
    As[acol + 2][arow] = av.z;
    As[acol + 3][arow] = av.w;
    *(float4*)&Bs[brow][bcol] = bv;
    __syncthreads();
#pragma unroll
    for (int k = 0; k < 8; ++k) {
      const float4 a0 = *(const float4*)&As[k][ty * 8];
      const float4 a1 = *(const float4*)&As[k][ty * 8 + 4];
      const float4 b0 = *(const float4*)&Bs[k][tx * 8];
      const float4 b1 = *(const float4*)&Bs[k][tx * 8 + 4];
      const float am[8] = {a0.x, a0.y, a0.z, a0.w, a1.x, a1.y, a1.z, a1.w};
      const float bn[8] = {b0.x, b0.y, b0.z, b0.w, b1.x, b1.y, b1.z, b1.w};
#pragma unroll
      for (int i = 0; i < 8; ++i)
#pragma unroll
        for (int j = 0; j < 8; ++j)
          acc[i][j] = fmaf(am[i], bn[j], acc[i][j]);
    }
    __syncthreads();
  }

  const int n0 = bn0 + tx * 8;
  float bb[8];
#pragma unroll
  for (int j = 0; j < 8; ++j) bb[j] = bias[n0 + j];
#pragma unroll
  for (int i = 0; i < 8; ++i) {
    float* Crow = C + (long)(bm0 + ty * 8 + i) * N + n0;
    float r[8];
#pragma unroll
    for (int j = 0; j < 8; ++j) {
      float x = acc[i][j] + bb[j];
      if constexpr (ACT == 1) x = fmaxf(x, 0.f);
      else if constexpr (ACT == 2) x = tanhf(x);
      else if constexpr (ACT == 3) x = 1.f / (1.f + expf(-x));
      r[j] = x;
    }
    *(float4*)(Crow + 0) = make_float4(r[0], r[1], r[2], r[3]);
    *(float4*)(Crow + 4) = make_float4(r[4], r[5], r[6], r[7]);
  }
}

// ---------------------------------------------------------------------------
extern "C" void kernel_launch(void* const* d_in, const int* in_sizes, int n_in,
                              void* d_out, int out_size, void* d_ws, size_t ws_size,
                              hipStream_t stream) {
  const int*   ids   = (const int*)d_in[0];
  const float* table = (const float*)d_in[1];
  const float* en_g  = (const float*)d_in[2];
  const float* en_b  = (const float*)d_in[3];
  const float* w00 = (const float*)d_in[4];
  const float* b00 = (const float*)d_in[5];
  const float* w01 = (const float*)d_in[6];
  const float* b01 = (const float*)d_in[7];
  const float* w10 = (const float*)d_in[8];
  const float* b10 = (const float*)d_in[9];
  const float* w11 = (const float*)d_in[10];
  const float* b11 = (const float*)d_in[11];
  const float* dw0 = (const float*)d_in[12];
  const float* db0 = (const float*)d_in[13];
  const float* fw0 = (const float*)d_in[14];
  const float* fb0 = (const float*)d_in[15];
  const float* iw0 = (const float*)d_in[16];
  const float* ib0 = (const float*)d_in[17];
  const float* cg0 = (const float*)d_in[18];
  const float* cb0 = (const float*)d_in[19];
  // block-1 gates (d_in[20..27]) are dead w.r.t. logits -> unused
  const float* ow  = (const float*)d_in[28];
  const float* ob  = (const float*)d_in[29];

  float* ws   = (float*)d_ws;
  float* hcat = ws;                                  // [T, E+C]
  float* h1   = hcat + (long)T_TOK * (E_DIM + C_DIM);// [T, H]
  float* h2   = h1 + (long)T_TOK * H_DIM;            // [T, H]
  float* dbuf = h2 + (long)T_TOK * H_DIM;            // [T, C]
  float* fbuf = dbuf + (long)T_TOK * C_DIM;          // [T, C]
  float* ibuf = fbuf + (long)T_TOK * C_DIM;          // [T, C]
  float* out  = (float*)d_out;                       // [T, V]

  const dim3 blk(256);
  const dim3 gH(H_DIM / 128, T_TOK / 128);
  const dim3 gC(C_DIM / 128, T_TOK / 128);
  const dim3 gV(V_DIM / 128, T_TOK / 128);

  // x = LN(embed[ids]); ctx = 0  (both stored into hcat rows)
  embed_ln_kernel<<<T_TOK, blk, 0, stream>>>(ids, table, en_g, en_b, hcat);

  // ---- block 0 ----
  gemm_bias_act<1><<<gH, blk, 0, stream>>>(hcat, w00, b00, h1, T_TOK, H_DIM, E_DIM + C_DIM);
  gemm_bias_act<1><<<gH, blk, 0, stream>>>(h1,   w01, b01, h2, T_TOK, H_DIM, H_DIM);
  gemm_bias_act<2><<<gC, blk, 0, stream>>>(h2, dw0, db0, dbuf, T_TOK, C_DIM, H_DIM);
  gemm_bias_act<3><<<gC, blk, 0, stream>>>(h2, fw0, fb0, fbuf, T_TOK, C_DIM, H_DIM);
  gemm_bias_act<3><<<gC, blk, 0, stream>>>(h2, iw0, ib0, ibuf, T_TOK, C_DIM, H_DIM);
  ctx_ln_kernel<<<T_TOK, blk, 0, stream>>>(fbuf, ibuf, dbuf, cg0, cb0, hcat);

  // ---- block 1 (gates/ctx dead -> only the two Linear+ReLU) ----
  gemm_bias_act<1><<<gH, blk, 0, stream>>>(hcat, w10, b10, h1, T_TOK, H_DIM, E_DIM + C_DIM);
  gemm_bias_act<1><<<gH, blk, 0, stream>>>(h1,   w11, b11, h2, T_TOK, H_DIM, H_DIM);

  // ---- logits ----
  gemm_bias_act<0><<<gV, blk, 0, stream>>>(h2, ow, ob, out, T_TOK, V_DIM, H_DIM);
}